// Round 1
// baseline (1400.640 us; speedup 1.0000x reference)
//
#include <hip/hip_runtime.h>
#include <cstddef>

#define DIM 128

__device__ __forceinline__ float leaky(float v) {
    return v > 0.0f ? v : 0.01f * v;
}

// ---------------------------------------------------------------------------
// Kernel 1: accumulate edge weights into deg[col]  (self-loop +1 folded later)
// ---------------------------------------------------------------------------
__global__ __launch_bounds__(256)
void deg_kernel(const int* __restrict__ col, const float* __restrict__ w,
                float* __restrict__ deg, int E) {
    int e = blockIdx.x * blockDim.x + threadIdx.x;
    if (e < E) {
        unsafeAtomicAdd(&deg[col[e]], w[e]);
    }
}

// ---------------------------------------------------------------------------
// Kernel 2: fused dual GEMM  h = x@Wg ; f = leaky(x@Wf + bf)
//   writes: hs   = dinv * h                      (ws)
//           dinv = rsqrt(deg+1)                  (ws)
//           acc  = f + bg + dinv^2 * h           (d_out; self-loop message)
// block = 256 threads: g = tid>>5 (8 row groups x 4 rows), j4 = tid&31
// (4 cols each). Block covers 32 rows x 128 cols of both outputs.
// ---------------------------------------------------------------------------
__global__ __launch_bounds__(256)
void gemm_fused_kernel(const float* __restrict__ x_src, const float* __restrict__ x_tar,
                       int n_src, int n_total,
                       const float* __restrict__ Wg, const float* __restrict__ bg,
                       const float* __restrict__ Wf, const float* __restrict__ bf,
                       const float* __restrict__ deg,
                       float* __restrict__ hs, float* __restrict__ dinvbuf,
                       float* __restrict__ acc)
{
    const int tid = threadIdx.x;
    const int j4  = tid & 31;            // cols j4*4 .. j4*4+3
    const int g   = tid >> 5;            // row group
    const int rowbase = blockIdx.x * 32 + g * 4;

    float accg[4][4];
    float accf[4][4];
#pragma unroll
    for (int r = 0; r < 4; ++r)
#pragma unroll
        for (int c = 0; c < 4; ++c) { accg[r][c] = 0.0f; accf[r][c] = 0.0f; }

    const float* xp[4];
#pragma unroll
    for (int r = 0; r < 4; ++r) {
        int i = rowbase + r;
        if (i >= n_total) i = n_total - 1;      // clamp (grid is exact anyway)
        xp[r] = (i < n_src) ? (x_src + (size_t)i * DIM)
                            : (x_tar + (size_t)(i - n_src) * DIM);
    }

    for (int kk = 0; kk < DIM; kk += 4) {
        float4 xv[4];
#pragma unroll
        for (int r = 0; r < 4; ++r)
            xv[r] = *(const float4*)(xp[r] + kk);

        float4 wg[4], wf[4];
#pragma unroll
        for (int m = 0; m < 4; ++m) {
            wg[m] = *(const float4*)(Wg + (size_t)(kk + m) * DIM + j4 * 4);
            wf[m] = *(const float4*)(Wf + (size_t)(kk + m) * DIM + j4 * 4);
        }

#pragma unroll
        for (int m = 0; m < 4; ++m) {
#pragma unroll
            for (int r = 0; r < 4; ++r) {
                const float xs = ((const float*)&xv[r])[m];
                accg[r][0] += xs * wg[m].x;
                accg[r][1] += xs * wg[m].y;
                accg[r][2] += xs * wg[m].z;
                accg[r][3] += xs * wg[m].w;
                accf[r][0] += xs * wf[m].x;
                accf[r][1] += xs * wf[m].y;
                accf[r][2] += xs * wf[m].z;
                accf[r][3] += xs * wf[m].w;
            }
        }
    }

    const float4 bgv = *(const float4*)(bg + j4 * 4);
    const float4 bfv = *(const float4*)(bf + j4 * 4);

#pragma unroll
    for (int r = 0; r < 4; ++r) {
        int i = rowbase + r;
        if (i >= n_total) continue;
        float dv = rsqrtf(deg[i] + 1.0f);       // self-loop weight 1 included
        if (j4 == 0) dinvbuf[i] = dv;

        float4 hsv;
        hsv.x = dv * accg[r][0];
        hsv.y = dv * accg[r][1];
        hsv.z = dv * accg[r][2];
        hsv.w = dv * accg[r][3];

        float4 av;
        av.x = leaky(accf[r][0] + bfv.x) + bgv.x + dv * hsv.x;
        av.y = leaky(accf[r][1] + bfv.y) + bgv.y + dv * hsv.y;
        av.z = leaky(accf[r][2] + bfv.z) + bgv.z + dv * hsv.z;
        av.w = leaky(accf[r][3] + bfv.w) + bgv.w + dv * hsv.w;

        *(float4*)(hs  + (size_t)i * DIM + j4 * 4) = hsv;
        *(float4*)(acc + (size_t)i * DIM + j4 * 4) = av;
    }
}

// ---------------------------------------------------------------------------
// Kernel 3: edge scatter.  32 lanes per edge, each lane owns 4 dims.
//   acc[col] += (w * dinv[col]) * hs[row]
// ---------------------------------------------------------------------------
__global__ __launch_bounds__(256)
void edge_kernel(const int* __restrict__ row, const int* __restrict__ col,
                 const float* __restrict__ w, const float* __restrict__ dinv,
                 const float* __restrict__ hs, float* __restrict__ acc, int E)
{
    int t = blockIdx.x * 256 + threadIdx.x;
    int e = t >> 5;
    int lane = t & 31;
    if (e >= E) return;
    int r = row[e];
    int c = col[e];
    float m = w[e] * dinv[c];
    float4 v = ((const float4*)(hs + (size_t)r * DIM))[lane];
    float* dst = acc + (size_t)c * DIM + lane * 4;
    unsafeAtomicAdd(dst + 0, m * v.x);
    unsafeAtomicAdd(dst + 1, m * v.y);
    unsafeAtomicAdd(dst + 2, m * v.z);
    unsafeAtomicAdd(dst + 3, m * v.w);
}

// ---------------------------------------------------------------------------
// Kernel 4: in-place row layernorm (eps inside sqrt) + leaky_relu
// one 64-lane wave per row, 2 floats per lane; two-pass mean/var
// ---------------------------------------------------------------------------
__global__ __launch_bounds__(256)
void norm_kernel(float* __restrict__ acc, int n)
{
    int wid  = threadIdx.x >> 6;
    int lane = threadIdx.x & 63;
    int i = blockIdx.x * 4 + wid;
    if (i >= n) return;

    float2 v = *(const float2*)(acc + (size_t)i * DIM + lane * 2);

    float s = v.x + v.y;
#pragma unroll
    for (int m = 1; m < 64; m <<= 1) s += __shfl_xor(s, m, 64);
    float mean = s * (1.0f / 128.0f);

    float cx = v.x - mean, cy = v.y - mean;
    float sq = cx * cx + cy * cy;
#pragma unroll
    for (int m = 1; m < 64; m <<= 1) sq += __shfl_xor(sq, m, 64);
    float var = sq * (1.0f / 128.0f);
    float rstd = rsqrtf(var + 1e-6f);

    float2 o;
    o.x = leaky(cx * rstd);
    o.y = leaky(cy * rstd);
    *(float2*)(acc + (size_t)i * DIM + lane * 2) = o;
}

// ---------------------------------------------------------------------------
extern "C" void kernel_launch(void* const* d_in, const int* in_sizes, int n_in,
                              void* d_out, int out_size, void* d_ws, size_t ws_size,
                              hipStream_t stream)
{
    const float* x_src = (const float*)d_in[0];
    const float* x_tar = (const float*)d_in[1];
    const int*   ei    = (const int*)d_in[2];
    const float* ew    = (const float*)d_in[3];
    const float* Wg    = (const float*)d_in[4];
    const float* bg    = (const float*)d_in[5];
    const float* Wf    = (const float*)d_in[6];
    const float* bf    = (const float*)d_in[7];

    const int n_src = in_sizes[0] / DIM;
    const int n_tar = in_sizes[1] / DIM;
    const int N     = n_src + n_tar;
    const int E     = in_sizes[3];

    const int* rowp = ei;       // edge_index[0] = message source
    const int* colp = ei + E;   // edge_index[1] = message target

    float* deg  = (float*)d_ws;          // N floats
    float* dinv = deg + N;               // N floats
    float* hs   = dinv + N;              // N*DIM floats
    float* acc  = (float*)d_out;         // N*DIM floats (accumulator + output)

    hipMemsetAsync(deg, 0, (size_t)N * sizeof(float), stream);

    deg_kernel<<<(E + 255) / 256, 256, 0, stream>>>(colp, ew, deg, E);

    gemm_fused_kernel<<<(N + 31) / 32, 256, 0, stream>>>(
        x_src, x_tar, n_src, N, Wg, bg, Wf, bf, deg, hs, dinv, acc);

    edge_kernel<<<((size_t)E * 32 + 255) / 256, 256, 0, stream>>>(
        rowp, colp, ew, dinv, hs, acc, E);

    norm_kernel<<<(N + 3) / 4, 256, 0, stream>>>(acc, N);
}

// Round 2
// 542.733 us; speedup vs baseline: 2.5807x; 2.5807x over previous
//
#include <hip/hip_runtime.h>
#include <cstddef>

#define DIM 128
#define SCAN_CHUNK 2048   // 256 threads x 8 elems

__device__ __forceinline__ float leaky(float v) {
    return v > 0.0f ? v : 0.01f * v;
}

// ---------------------------------------------------------------------------
// Kernel 1: histogram of in-degree (counts) + weighted degree
// ---------------------------------------------------------------------------
__global__ __launch_bounds__(256)
void hist_deg_kernel(const int* __restrict__ col, const float* __restrict__ w,
                     int* __restrict__ cnt, float* __restrict__ deg, int E) {
    int e = blockIdx.x * blockDim.x + threadIdx.x;
    if (e < E) {
        int c = col[e];
        atomicAdd(&cnt[c], 1);
        unsafeAtomicAdd(&deg[c], w[e]);
    }
}

// ---------------------------------------------------------------------------
// Scan pass 1: per-block (2048-elem chunk) sums of cnt (padded with 0 past N)
// ---------------------------------------------------------------------------
__global__ __launch_bounds__(256)
void scan_block_sums(const int* __restrict__ cnt, int* __restrict__ bsum, int N) {
    __shared__ int sdata[4];
    int base = blockIdx.x * SCAN_CHUNK;
    int s = 0;
    for (int k = threadIdx.x; k < SCAN_CHUNK; k += 256) {
        int idx = base + k;
        s += (idx < N) ? cnt[idx] : 0;
    }
#pragma unroll
    for (int m = 1; m < 64; m <<= 1) s += __shfl_xor(s, m, 64);
    if ((threadIdx.x & 63) == 0) sdata[threadIdx.x >> 6] = s;
    __syncthreads();
    if (threadIdx.x == 0)
        bsum[blockIdx.x] = sdata[0] + sdata[1] + sdata[2] + sdata[3];
}

// ---------------------------------------------------------------------------
// Scan pass 2: exclusive scan of block sums (nb <= 128), single block of 128
// ---------------------------------------------------------------------------
__global__ __launch_bounds__(128)
void scan_bsum_kernel(int* __restrict__ bsum, int nb) {
    __shared__ int wtot[2];
    int t = threadIdx.x;
    int lane = t & 63;
    int orig = (t < nb) ? bsum[t] : 0;
    int v = orig;
#pragma unroll
    for (int m = 1; m < 64; m <<= 1) {
        int u = __shfl_up(v, m, 64);
        if (lane >= m) v += u;
    }
    if (lane == 63) wtot[t >> 6] = v;
    __syncthreads();
    if (t >= 64) v += wtot[0];
    if (t < nb) bsum[t] = v - orig;   // exclusive
}

// ---------------------------------------------------------------------------
// Scan pass 3: write exclusive scan to off[0..N] and cursor copy into cnt[]
// (cnt is re-used as the mutable cursor for the reorder pass)
// ---------------------------------------------------------------------------
__global__ __launch_bounds__(256)
void scan_write_kernel(int* __restrict__ cnt, const int* __restrict__ bsum,
                       int* __restrict__ off, int N) {
    __shared__ int wsum[4];
    int t = threadIdx.x;
    int base = blockIdx.x * SCAN_CHUNK + t * 8;
    int vals[8];
    int local = 0;
#pragma unroll
    for (int k = 0; k < 8; ++k) {
        int idx = base + k;
        int c = (idx < N) ? cnt[idx] : 0;
        vals[k] = local;
        local += c;
    }
    int tsum = local;
    int lane = t & 63;
    int v = tsum;
#pragma unroll
    for (int m = 1; m < 64; m <<= 1) {
        int u = __shfl_up(v, m, 64);
        if (lane >= m) v += u;
    }
    if (lane == 63) wsum[t >> 6] = v;
    __syncthreads();
    int woff = 0;
    for (int i = 0; i < (t >> 6); ++i) woff += wsum[i];
    int texcl = (v - tsum) + woff + bsum[blockIdx.x];
#pragma unroll
    for (int k = 0; k < 8; ++k) {
        int idx = base + k;
        int o = texcl + vals[k];
        if (idx <= N) off[idx] = o;
    }
    // cursor copy (only N entries needed) — written AFTER all reads of cnt in
    // this block are done (vals already captured above)
    __syncthreads();
#pragma unroll
    for (int k = 0; k < 8; ++k) {
        int idx = base + k;
        int o = texcl + vals[k];
        if (idx < N) cnt[idx] = o;
    }
}

// ---------------------------------------------------------------------------
// Reorder: place each edge's (row, w) into CSR slots by target node
// ---------------------------------------------------------------------------
__global__ __launch_bounds__(256)
void reorder_kernel(const int* __restrict__ row, const int* __restrict__ col,
                    const float* __restrict__ w, int* __restrict__ cursor,
                    int* __restrict__ rowR, float* __restrict__ wR, int E) {
    int e = blockIdx.x * blockDim.x + threadIdx.x;
    if (e < E) {
        int c = col[e];
        int pos = atomicAdd(&cursor[c], 1);
        rowR[pos] = row[e];
        wR[pos]  = w[e];
    }
}

// ---------------------------------------------------------------------------
// Fused dual GEMM  h = x@Wg ; f = leaky(x@Wf + bf)
//   writes: hs   = dinv * h                      (ws)
//           dinv = rsqrt(deg+1)                  (ws)
//           acc  = f + bg + dinv^2 * h           (d_out; self-loop message)
// ---------------------------------------------------------------------------
__global__ __launch_bounds__(256)
void gemm_fused_kernel(const float* __restrict__ x_src, const float* __restrict__ x_tar,
                       int n_src, int n_total,
                       const float* __restrict__ Wg, const float* __restrict__ bg,
                       const float* __restrict__ Wf, const float* __restrict__ bf,
                       const float* __restrict__ deg,
                       float* __restrict__ hs, float* __restrict__ dinvbuf,
                       float* __restrict__ acc)
{
    const int tid = threadIdx.x;
    const int j4  = tid & 31;            // cols j4*4 .. j4*4+3
    const int g   = tid >> 5;            // row group
    const int rowbase = blockIdx.x * 32 + g * 4;

    float accg[4][4];
    float accf[4][4];
#pragma unroll
    for (int r = 0; r < 4; ++r)
#pragma unroll
        for (int c = 0; c < 4; ++c) { accg[r][c] = 0.0f; accf[r][c] = 0.0f; }

    const float* xp[4];
#pragma unroll
    for (int r = 0; r < 4; ++r) {
        int i = rowbase + r;
        if (i >= n_total) i = n_total - 1;
        xp[r] = (i < n_src) ? (x_src + (size_t)i * DIM)
                            : (x_tar + (size_t)(i - n_src) * DIM);
    }

    for (int kk = 0; kk < DIM; kk += 4) {
        float4 xv[4];
#pragma unroll
        for (int r = 0; r < 4; ++r)
            xv[r] = *(const float4*)(xp[r] + kk);

        float4 wg[4], wf[4];
#pragma unroll
        for (int m = 0; m < 4; ++m) {
            wg[m] = *(const float4*)(Wg + (size_t)(kk + m) * DIM + j4 * 4);
            wf[m] = *(const float4*)(Wf + (size_t)(kk + m) * DIM + j4 * 4);
        }

#pragma unroll
        for (int m = 0; m < 4; ++m) {
#pragma unroll
            for (int r = 0; r < 4; ++r) {
                const float xs = ((const float*)&xv[r])[m];
                accg[r][0] += xs * wg[m].x;
                accg[r][1] += xs * wg[m].y;
                accg[r][2] += xs * wg[m].z;
                accg[r][3] += xs * wg[m].w;
                accf[r][0] += xs * wf[m].x;
                accf[r][1] += xs * wf[m].y;
                accf[r][2] += xs * wf[m].z;
                accf[r][3] += xs * wf[m].w;
            }
        }
    }

    const float4 bgv = *(const float4*)(bg + j4 * 4);
    const float4 bfv = *(const float4*)(bf + j4 * 4);

#pragma unroll
    for (int r = 0; r < 4; ++r) {
        int i = rowbase + r;
        if (i >= n_total) continue;
        float dv = rsqrtf(deg[i] + 1.0f);
        if (j4 == 0) dinvbuf[i] = dv;

        float4 hsv;
        hsv.x = dv * accg[r][0];
        hsv.y = dv * accg[r][1];
        hsv.z = dv * accg[r][2];
        hsv.w = dv * accg[r][3];

        float4 av;
        av.x = leaky(accf[r][0] + bfv.x) + bgv.x + dv * hsv.x;
        av.y = leaky(accf[r][1] + bfv.y) + bgv.y + dv * hsv.y;
        av.z = leaky(accf[r][2] + bfv.z) + bgv.z + dv * hsv.z;
        av.w = leaky(accf[r][3] + bfv.w) + bgv.w + dv * hsv.w;

        *(float4*)(hs  + (size_t)i * DIM + j4 * 4) = hsv;
        *(float4*)(acc + (size_t)i * DIM + j4 * 4) = av;
    }
}

// ---------------------------------------------------------------------------
// Gather + fused layernorm + leaky_relu.
// One 64-lane wave per target node; lane owns 2 dims (float2).
//   out[i] = norm( acc[i] + dinv[i] * sum_{e->i} w_e * hs[row_e] )
// ---------------------------------------------------------------------------
__global__ __launch_bounds__(256)
void gather_norm_kernel(const int* __restrict__ off, const int* __restrict__ rowR,
                        const float* __restrict__ wR, const float* __restrict__ dinv,
                        const float* __restrict__ hs, float* __restrict__ acc, int n)
{
    int wid  = threadIdx.x >> 6;
    int lane = threadIdx.x & 63;
    int i = blockIdx.x * 4 + wid;
    if (i >= n) return;

    int start = off[i];
    int end   = off[i + 1];

    float2 s = make_float2(0.0f, 0.0f);
    for (int j = start; j < end; ++j) {
        int r    = rowR[j];
        float wv = wR[j];
        float2 h = *(const float2*)(hs + (size_t)r * DIM + lane * 2);
        s.x += wv * h.x;
        s.y += wv * h.y;
    }

    float dv = dinv[i];
    float2 a = *(const float2*)(acc + (size_t)i * DIM + lane * 2);
    float vx = a.x + dv * s.x;
    float vy = a.y + dv * s.y;

    // fused node-norm + leaky
    float sum = vx + vy;
#pragma unroll
    for (int m = 1; m < 64; m <<= 1) sum += __shfl_xor(sum, m, 64);
    float mean = sum * (1.0f / 128.0f);

    float cx = vx - mean, cy = vy - mean;
    float sq = cx * cx + cy * cy;
#pragma unroll
    for (int m = 1; m < 64; m <<= 1) sq += __shfl_xor(sq, m, 64);
    float rstd = rsqrtf(sq * (1.0f / 128.0f) + 1e-6f);

    float2 o;
    o.x = leaky(cx * rstd);
    o.y = leaky(cy * rstd);
    *(float2*)(acc + (size_t)i * DIM + lane * 2) = o;
}

// ---------------------------------------------------------------------------
extern "C" void kernel_launch(void* const* d_in, const int* in_sizes, int n_in,
                              void* d_out, int out_size, void* d_ws, size_t ws_size,
                              hipStream_t stream)
{
    const float* x_src = (const float*)d_in[0];
    const float* x_tar = (const float*)d_in[1];
    const int*   ei    = (const int*)d_in[2];
    const float* ew    = (const float*)d_in[3];
    const float* Wg    = (const float*)d_in[4];
    const float* bg    = (const float*)d_in[5];
    const float* Wf    = (const float*)d_in[6];
    const float* bf    = (const float*)d_in[7];

    const int n_src = in_sizes[0] / DIM;
    const int n_tar = in_sizes[1] / DIM;
    const int N     = n_src + n_tar;
    const int E     = in_sizes[3];

    const int* rowp = ei;       // edge_index[0] = message source
    const int* colp = ei + E;   // edge_index[1] = message target

    // workspace layout
    float* deg   = (float*)d_ws;                 // N
    int*   cnt   = (int*)(deg + N);              // N (later: cursor)
    float* dinv  = (float*)(cnt + N);            // N
    int*   off   = (int*)(dinv + N);             // N+1
    int*   bsum  = off + (N + 1);                // 128 (pad to 131 -> align)
    int*   rowR  = bsum + 128;                   // E
    float* wR    = (float*)(rowR + E);           // E
    float* hs    = wR + E;                       // N*DIM
    // total floats: 4N+1+128+2E+N*128  ~= 110 MB for N=200k,E=600k

    const int NB = (N + 1 + SCAN_CHUNK - 1) / SCAN_CHUNK;

    hipMemsetAsync(deg, 0, (size_t)2 * N * sizeof(float), stream);  // deg + cnt

    hist_deg_kernel<<<(E + 255) / 256, 256, 0, stream>>>(colp, ew, cnt, deg, E);

    scan_block_sums<<<NB, 256, 0, stream>>>(cnt, bsum, N);
    scan_bsum_kernel<<<1, 128, 0, stream>>>(bsum, NB);
    scan_write_kernel<<<NB, 256, 0, stream>>>(cnt, bsum, off, N);

    reorder_kernel<<<(E + 255) / 256, 256, 0, stream>>>(rowp, colp, ew, cnt,
                                                        rowR, wR, E);

    gemm_fused_kernel<<<(N + 31) / 32, 256, 0, stream>>>(
        x_src, x_tar, n_src, N, Wg, bg, Wf, bf, deg, hs, dinv, (float*)d_out);

    gather_norm_kernel<<<(N + 3) / 4, 256, 0, stream>>>(
        off, rowR, wR, dinv, hs, (float*)d_out, N);
}

// Round 3
// 289.867 us; speedup vs baseline: 4.8320x; 1.8723x over previous
//
#include <hip/hip_runtime.h>
#include <cstddef>
#include <cstdint>

#define DIM 128
#define SCAN_CHUNK 2048   // 256 threads x 8 elems

typedef __attribute__((ext_vector_type(8))) short short8v;  // 8 bf16 (4 VGPR)
typedef __attribute__((ext_vector_type(4))) float f32x4;    // MFMA acc

__device__ __forceinline__ float leaky(float v) {
    return v > 0.0f ? v : 0.01f * v;
}

__device__ __forceinline__ unsigned short f2bf(float f) {
    unsigned u = __builtin_bit_cast(unsigned, f);
    u += 0x7FFF + ((u >> 16) & 1);      // round-to-nearest-even
    return (unsigned short)(u >> 16);
}

__device__ __forceinline__ float bf2f_hi(unsigned p) {      // high ushort
    return __builtin_bit_cast(float, p & 0xFFFF0000u);
}
__device__ __forceinline__ float bf2f_lo(unsigned p) {      // low ushort
    return __builtin_bit_cast(float, p << 16);
}

// ---------------------------------------------------------------------------
// Kernel 1: histogram of in-degree (counts) + weighted degree
// ---------------------------------------------------------------------------
__global__ __launch_bounds__(256)
void hist_deg_kernel(const int* __restrict__ col, const float* __restrict__ w,
                     int* __restrict__ cnt, float* __restrict__ deg, int E) {
    int e = blockIdx.x * blockDim.x + threadIdx.x;
    if (e < E) {
        int c = col[e];
        atomicAdd(&cnt[c], 1);
        unsafeAtomicAdd(&deg[c], w[e]);
    }
}

// ---------------------------------------------------------------------------
// dinv[i] = rsqrt(deg[i] + 1)   (self-loop weight 1 folded)
// ---------------------------------------------------------------------------
__global__ __launch_bounds__(256)
void dinv_kernel(const float* __restrict__ deg, float* __restrict__ dinv, int n) {
    int i = blockIdx.x * 256 + threadIdx.x;
    if (i < n) dinv[i] = rsqrtf(deg[i] + 1.0f);
}

// ---------------------------------------------------------------------------
// W prep: WgT[col][k] = bf16(Wg[k][col]); same for Wf. 128x128 each.
// ---------------------------------------------------------------------------
__global__ __launch_bounds__(256)
void wprep_kernel(const float* __restrict__ Wg, const float* __restrict__ Wf,
                  unsigned short* __restrict__ WgT, unsigned short* __restrict__ WfT) {
    int t = blockIdx.x * 256 + threadIdx.x;   // 0..16383
    int col = t >> 7, k = t & 127;
    WgT[col * 128 + k] = f2bf(Wg[k * 128 + col]);
    WfT[col * 128 + k] = f2bf(Wf[k * 128 + col]);
}

// ---------------------------------------------------------------------------
// Scan pass 1: per-block (2048-elem chunk) sums of cnt
// ---------------------------------------------------------------------------
__global__ __launch_bounds__(256)
void scan_block_sums(const int* __restrict__ cnt, int* __restrict__ bsum, int N) {
    __shared__ int sdata[4];
    int base = blockIdx.x * SCAN_CHUNK;
    int s = 0;
    for (int k = threadIdx.x; k < SCAN_CHUNK; k += 256) {
        int idx = base + k;
        s += (idx < N) ? cnt[idx] : 0;
    }
#pragma unroll
    for (int m = 1; m < 64; m <<= 1) s += __shfl_xor(s, m, 64);
    if ((threadIdx.x & 63) == 0) sdata[threadIdx.x >> 6] = s;
    __syncthreads();
    if (threadIdx.x == 0)
        bsum[blockIdx.x] = sdata[0] + sdata[1] + sdata[2] + sdata[3];
}

// ---------------------------------------------------------------------------
// Scan pass 2: exclusive scan of block sums (nb <= 128)
// ---------------------------------------------------------------------------
__global__ __launch_bounds__(128)
void scan_bsum_kernel(int* __restrict__ bsum, int nb) {
    __shared__ int wtot[2];
    int t = threadIdx.x;
    int lane = t & 63;
    int orig = (t < nb) ? bsum[t] : 0;
    int v = orig;
#pragma unroll
    for (int m = 1; m < 64; m <<= 1) {
        int u = __shfl_up(v, m, 64);
        if (lane >= m) v += u;
    }
    if (lane == 63) wtot[t >> 6] = v;
    __syncthreads();
    if (t >= 64) v += wtot[0];
    if (t < nb) bsum[t] = v - orig;   // exclusive
}

// ---------------------------------------------------------------------------
// Scan pass 3: exclusive scan -> off[0..N], cursor copy into cnt[]
// ---------------------------------------------------------------------------
__global__ __launch_bounds__(256)
void scan_write_kernel(int* __restrict__ cnt, const int* __restrict__ bsum,
                       int* __restrict__ off, int N) {
    __shared__ int wsum[4];
    int t = threadIdx.x;
    int base = blockIdx.x * SCAN_CHUNK + t * 8;
    int vals[8];
    int local = 0;
#pragma unroll
    for (int k = 0; k < 8; ++k) {
        int idx = base + k;
        int c = (idx < N) ? cnt[idx] : 0;
        vals[k] = local;
        local += c;
    }
    int tsum = local;
    int lane = t & 63;
    int v = tsum;
#pragma unroll
    for (int m = 1; m < 64; m <<= 1) {
        int u = __shfl_up(v, m, 64);
        if (lane >= m) v += u;
    }
    if (lane == 63) wsum[t >> 6] = v;
    __syncthreads();
    int woff = 0;
    for (int i = 0; i < (t >> 6); ++i) woff += wsum[i];
    int texcl = (v - tsum) + woff + bsum[blockIdx.x];
#pragma unroll
    for (int k = 0; k < 8; ++k) {
        int idx = base + k;
        int o = texcl + vals[k];
        if (idx <= N) off[idx] = o;
    }
    __syncthreads();
#pragma unroll
    for (int k = 0; k < 8; ++k) {
        int idx = base + k;
        int o = texcl + vals[k];
        if (idx < N) cnt[idx] = o;
    }
}

// ---------------------------------------------------------------------------
// Reorder edges into CSR-by-target
// ---------------------------------------------------------------------------
__global__ __launch_bounds__(256)
void reorder_kernel(const int* __restrict__ row, const int* __restrict__ col,
                    const float* __restrict__ w, int* __restrict__ cursor,
                    int* __restrict__ rowR, float* __restrict__ wR, int E) {
    int e = blockIdx.x * blockDim.x + threadIdx.x;
    if (e < E) {
        int c = col[e];
        int pos = atomicAdd(&cursor[c], 1);
        rowR[pos] = row[e];
        wR[pos]  = w[e];
    }
}

// ---------------------------------------------------------------------------
// MFMA dual GEMM:  h = x@Wg ; f = x@Wf  (A shared, bf16 matrix cores)
//   per block: 128 rows x (128 cols of BOTH outputs)
//   4 waves, each: 64 rows x 64 cols, accg + accf (lane-local epilogue)
//   epilogue:  hs   = bf16(dinv*h)
//              out  = leaky(f + bf) + bg + dinv*(dinv*h)   (self-loop folded)
// LDS A-tile: [128 rows][16 chunks of 16B], chunk XOR-swizzled by (row&15)
// ---------------------------------------------------------------------------
__global__ __launch_bounds__(256, 2)
void gemm_mfma_kernel(const float* __restrict__ x_src, const float* __restrict__ x_tar,
                      int n_src, int n_total,
                      const unsigned short* __restrict__ WgT,
                      const unsigned short* __restrict__ WfT,
                      const float* __restrict__ bg, const float* __restrict__ bf,
                      const float* __restrict__ dinv,
                      unsigned short* __restrict__ hsb, float* __restrict__ out)
{
    __shared__ unsigned short Ash[128 * 128];   // 32 KB bf16

    const int t = threadIdx.x;

    // ---- stage A: 128 rows x 128 f32 -> bf16, swizzled ----
#pragma unroll
    for (int s = 0; s < 8; ++s) {
        int id  = t + s * 256;        // 0..2047 chunk id
        int row = id >> 4;            // 0..127
        int c   = id & 15;            // 16B chunk within row
        int rg  = blockIdx.x * 128 + row;
        if (rg > n_total - 1) rg = n_total - 1;
        const float* xr = (rg < n_src) ? x_src + (size_t)rg * DIM
                                       : x_tar + (size_t)(rg - n_src) * DIM;
        float4 v0 = *(const float4*)(xr + c * 8);
        float4 v1 = *(const float4*)(xr + c * 8 + 4);
        union { uint4 q; unsigned short us[8]; } cv;
        cv.us[0] = f2bf(v0.x); cv.us[1] = f2bf(v0.y);
        cv.us[2] = f2bf(v0.z); cv.us[3] = f2bf(v0.w);
        cv.us[4] = f2bf(v1.x); cv.us[5] = f2bf(v1.y);
        cv.us[6] = f2bf(v1.z); cv.us[7] = f2bf(v1.w);
        *(uint4*)&Ash[(size_t)row * 128 + ((c ^ (row & 15)) * 8)] = cv.q;
    }
    __syncthreads();

    const int lane = t & 63;
    const int wave = t >> 6;
    const int wr = wave >> 1;         // row half (0..1)
    const int wc = wave & 1;          // col half (0..1)
    const int lr = lane & 15;
    const int lk = lane >> 4;

    f32x4 accg[4][4], accf[4][4];
#pragma unroll
    for (int i = 0; i < 4; ++i)
#pragma unroll
        for (int j = 0; j < 4; ++j) {
            accg[i][j] = (f32x4)0.0f;
            accf[i][j] = (f32x4)0.0f;
        }

#pragma unroll
    for (int ks = 0; ks < 4; ++ks) {
        short8v a[4];
#pragma unroll
        for (int mf = 0; mf < 4; ++mf) {
            int row = wr * 64 + mf * 16 + lr;      // A row, lane&15
            int cc  = ks * 4 + lk;                 // chunk = k/8
            a[mf] = *(const short8v*)&Ash[(size_t)row * 128 + ((cc ^ (row & 15)) * 8)];
        }
#pragma unroll
        for (int nf = 0; nf < 4; ++nf) {
            int col = wc * 64 + nf * 16 + lr;
            const size_t bo = (size_t)col * 128 + ks * 32 + lk * 8;
            short8v bgv = *(const short8v*)(WgT + bo);
            short8v bfv = *(const short8v*)(WfT + bo);
#pragma unroll
            for (int mf = 0; mf < 4; ++mf) {
                accg[mf][nf] = __builtin_amdgcn_mfma_f32_16x16x32_bf16(a[mf], bgv, accg[mf][nf], 0, 0, 0);
                accf[mf][nf] = __builtin_amdgcn_mfma_f32_16x16x32_bf16(a[mf], bfv, accf[mf][nf], 0, 0, 0);
            }
        }
    }

    // ---- epilogue: C/D layout col=lane&15, row=(lane>>4)*4+reg ----
#pragma unroll
    for (int mf = 0; mf < 4; ++mf) {
        int r0 = blockIdx.x * 128 + wr * 64 + mf * 16 + lk * 4;
        if (r0 >= n_total) continue;               // N%4==0 -> r0+3 < N
        float4 dv4 = *(const float4*)(dinv + r0);
#pragma unroll
        for (int nf = 0; nf < 4; ++nf) {
            int col = wc * 64 + nf * 16 + lr;
            float bgv = bg[col];
            float bfv = bf[col];
#pragma unroll
            for (int q = 0; q < 4; ++q) {
                size_t r  = (size_t)r0 + q;
                float dv  = ((const float*)&dv4)[q];
                float h   = accg[mf][nf][q];
                float f   = accf[mf][nf][q] + bfv;
                float hsv = dv * h;
                hsb[r * DIM + col] = f2bf(hsv);
                out[r * DIM + col] = leaky(f) + bgv + dv * hsv;
            }
        }
    }
}

// ---------------------------------------------------------------------------
// Gather + fused layernorm + leaky_relu. One wave per target node.
//   out[i] = norm( out[i] + dinv[i] * sum_{e->i} w_e * hs[row_e] )
// hs is bf16 (halves random-gather bytes; L3-resident)
// ---------------------------------------------------------------------------
__global__ __launch_bounds__(256)
void gather_norm_kernel(const int* __restrict__ off, const int* __restrict__ rowR,
                        const float* __restrict__ wR, const float* __restrict__ dinv,
                        const unsigned short* __restrict__ hsb,
                        float* __restrict__ acc, int n)
{
    int wid  = threadIdx.x >> 6;
    int lane = threadIdx.x & 63;
    int i = blockIdx.x * 4 + wid;
    if (i >= n) return;

    int start = off[i];
    int end   = off[i + 1];

    float sx = 0.0f, sy = 0.0f;
    for (int j = start; j < end; ++j) {
        int r    = rowR[j];
        float wv = wR[j];
        unsigned p = *(const unsigned*)(hsb + (size_t)r * DIM + lane * 2);
        sx += wv * bf2f_lo(p);
        sy += wv * bf2f_hi(p);
    }

    float dv = dinv[i];
    float2 a = *(const float2*)(acc + (size_t)i * DIM + lane * 2);
    float vx = a.x + dv * sx;
    float vy = a.y + dv * sy;

    float sum = vx + vy;
#pragma unroll
    for (int m = 1; m < 64; m <<= 1) sum += __shfl_xor(sum, m, 64);
    float mean = sum * (1.0f / 128.0f);

    float cx = vx - mean, cy = vy - mean;
    float sq = cx * cx + cy * cy;
#pragma unroll
    for (int m = 1; m < 64; m <<= 1) sq += __shfl_xor(sq, m, 64);
    float rstd = rsqrtf(sq * (1.0f / 128.0f) + 1e-6f);

    float2 o;
    o.x = leaky(cx * rstd);
    o.y = leaky(cy * rstd);
    *(float2*)(acc + (size_t)i * DIM + lane * 2) = o;
}

// ---------------------------------------------------------------------------
extern "C" void kernel_launch(void* const* d_in, const int* in_sizes, int n_in,
                              void* d_out, int out_size, void* d_ws, size_t ws_size,
                              hipStream_t stream)
{
    const float* x_src = (const float*)d_in[0];
    const float* x_tar = (const float*)d_in[1];
    const int*   ei    = (const int*)d_in[2];
    const float* ew    = (const float*)d_in[3];
    const float* Wg    = (const float*)d_in[4];
    const float* bg    = (const float*)d_in[5];
    const float* Wf    = (const float*)d_in[6];
    const float* bf    = (const float*)d_in[7];

    const int n_src = in_sizes[0] / DIM;
    const int n_tar = in_sizes[1] / DIM;
    const int N     = n_src + n_tar;
    const int E     = in_sizes[3];

    const int* rowp = ei;       // edge_index[0] = message source
    const int* colp = ei + E;   // edge_index[1] = message target

    // ---- workspace layout (bytes) ----
    char* p = (char*)d_ws;
    float* deg  = (float*)p;  p += (size_t)N * 4;
    int*   cnt  = (int*)p;    p += (size_t)N * 4;
    float* dinv = (float*)p;  p += (size_t)N * 4;
    int*   off  = (int*)p;    p += (size_t)(N + 1) * 4;
    int*   bsum = (int*)p;    p += 160 * 4;
    int*   rowR = (int*)p;    p += (size_t)E * 4;
    float* wR   = (float*)p;  p += (size_t)E * 4;
    p = (char*)(((uintptr_t)p + 15) & ~(uintptr_t)15);
    unsigned short* hsb = (unsigned short*)p; p += (size_t)N * DIM * 2;
    unsigned short* WgT = (unsigned short*)p; p += 128 * 128 * 2;
    unsigned short* WfT = (unsigned short*)p;

    const int NB = (N + 1 + SCAN_CHUNK - 1) / SCAN_CHUNK;

    hipMemsetAsync(deg, 0, (size_t)2 * N * sizeof(float), stream);  // deg + cnt

    wprep_kernel<<<64, 256, 0, stream>>>(Wg, Wf, WgT, WfT);

    hist_deg_kernel<<<(E + 255) / 256, 256, 0, stream>>>(colp, ew, cnt, deg, E);

    dinv_kernel<<<(N + 255) / 256, 256, 0, stream>>>(deg, dinv, N);

    scan_block_sums<<<NB, 256, 0, stream>>>(cnt, bsum, N);
    scan_bsum_kernel<<<1, 128, 0, stream>>>(bsum, NB);
    scan_write_kernel<<<NB, 256, 0, stream>>>(cnt, bsum, off, N);

    reorder_kernel<<<(E + 255) / 256, 256, 0, stream>>>(rowp, colp, ew, cnt,
                                                        rowR, wR, E);

    gemm_mfma_kernel<<<(N + 127) / 128, 256, 0, stream>>>(
        x_src, x_tar, n_src, N, WgT, WfT, bg, bf, dinv, hsb, (float*)d_out);

    gather_norm_kernel<<<(N + 3) / 4, 256, 0, stream>>>(
        off, rowR, wR, dinv, hsb, (float*)d_out, N);
}

// Round 4
// 246.853 us; speedup vs baseline: 5.6740x; 1.1742x over previous
//
#include <hip/hip_runtime.h>
#include <hip/hip_bf16.h>
#include <cstddef>
#include <cstdint>

#define DIM 128
#define SCAN_CHUNK 2048   // 256 threads x 8 elems

typedef __attribute__((ext_vector_type(8))) short short8v;  // 8 bf16 (4 VGPR)
typedef __attribute__((ext_vector_type(4))) float f32x4;    // MFMA acc

__device__ __forceinline__ float leaky(float v) {
    return v > 0.0f ? v : 0.01f * v;
}

__device__ __forceinline__ unsigned short f2bf(float f) {
    unsigned u = __builtin_bit_cast(unsigned, f);
    u += 0x7FFF + ((u >> 16) & 1);      // round-to-nearest-even
    return (unsigned short)(u >> 16);
}

__device__ __forceinline__ float bf2f_hi(unsigned p) {      // high ushort
    return __builtin_bit_cast(float, p & 0xFFFF0000u);
}
__device__ __forceinline__ float bf2f_lo(unsigned p) {      // low ushort
    return __builtin_bit_cast(float, p << 16);
}

// ---------------------------------------------------------------------------
// histogram of in-degree (counts) + weighted degree
// ---------------------------------------------------------------------------
__global__ __launch_bounds__(256)
void hist_deg_kernel(const int* __restrict__ col, const float* __restrict__ w,
                     int* __restrict__ cnt, float* __restrict__ deg, int E) {
    int e = blockIdx.x * blockDim.x + threadIdx.x;
    if (e < E) {
        int c = col[e];
        atomicAdd(&cnt[c], 1);
        unsafeAtomicAdd(&deg[c], w[e]);
    }
}

// ---------------------------------------------------------------------------
// in-place: dinv[i] = rsqrt(deg[i] + 1)
// ---------------------------------------------------------------------------
__global__ __launch_bounds__(256)
void dinv_kernel(float* __restrict__ d, int n) {
    int i = blockIdx.x * 256 + threadIdx.x;
    if (i < n) d[i] = rsqrtf(d[i] + 1.0f);
}

// ---------------------------------------------------------------------------
// W prep: WgT[col][k] = bf16(Wg[k][col]); same for Wf
// ---------------------------------------------------------------------------
__global__ __launch_bounds__(256)
void wprep_kernel(const float* __restrict__ Wg, const float* __restrict__ Wf,
                  unsigned short* __restrict__ WgT, unsigned short* __restrict__ WfT) {
    int t = blockIdx.x * 256 + threadIdx.x;   // 0..16383
    int col = t >> 7, k = t & 127;
    WgT[col * 128 + k] = f2bf(Wg[k * 128 + col]);
    WfT[col * 128 + k] = f2bf(Wf[k * 128 + col]);
}

// ---------------------------------------------------------------------------
// Scan pass 1: per-chunk sums of cnt
// ---------------------------------------------------------------------------
__global__ __launch_bounds__(256)
void scan_block_sums(const int* __restrict__ cnt, int* __restrict__ bsum, int N) {
    __shared__ int sdata[4];
    int base = blockIdx.x * SCAN_CHUNK;
    int s = 0;
    for (int k = threadIdx.x; k < SCAN_CHUNK; k += 256) {
        int idx = base + k;
        s += (idx < N) ? cnt[idx] : 0;
    }
#pragma unroll
    for (int m = 1; m < 64; m <<= 1) s += __shfl_xor(s, m, 64);
    if ((threadIdx.x & 63) == 0) sdata[threadIdx.x >> 6] = s;
    __syncthreads();
    if (threadIdx.x == 0)
        bsum[blockIdx.x] = sdata[0] + sdata[1] + sdata[2] + sdata[3];
}

// ---------------------------------------------------------------------------
// Scan pass 2: exclusive scan of chunk sums (nb <= 128)
// ---------------------------------------------------------------------------
__global__ __launch_bounds__(128)
void scan_bsum_kernel(int* __restrict__ bsum, int nb) {
    __shared__ int wtot[2];
    int t = threadIdx.x;
    int lane = t & 63;
    int orig = (t < nb) ? bsum[t] : 0;
    int v = orig;
#pragma unroll
    for (int m = 1; m < 64; m <<= 1) {
        int u = __shfl_up(v, m, 64);
        if (lane >= m) v += u;
    }
    if (lane == 63) wtot[t >> 6] = v;
    __syncthreads();
    if (t >= 64) v += wtot[0];
    if (t < nb) bsum[t] = v - orig;   // exclusive
}

// ---------------------------------------------------------------------------
// Scan pass 3: exclusive scan -> off[0..N], cursor copy into cnt[]
// ---------------------------------------------------------------------------
__global__ __launch_bounds__(256)
void scan_write_kernel(int* __restrict__ cnt, const int* __restrict__ bsum,
                       int* __restrict__ off, int N) {
    __shared__ int wsum[4];
    int t = threadIdx.x;
    int base = blockIdx.x * SCAN_CHUNK + t * 8;
    int vals[8];
    int local = 0;
#pragma unroll
    for (int k = 0; k < 8; ++k) {
        int idx = base + k;
        int c = (idx < N) ? cnt[idx] : 0;
        vals[k] = local;
        local += c;
    }
    int tsum = local;
    int lane = t & 63;
    int v = tsum;
#pragma unroll
    for (int m = 1; m < 64; m <<= 1) {
        int u = __shfl_up(v, m, 64);
        if (lane >= m) v += u;
    }
    if (lane == 63) wsum[t >> 6] = v;
    __syncthreads();
    int woff = 0;
    for (int i = 0; i < (t >> 6); ++i) woff += wsum[i];
    int texcl = (v - tsum) + woff + bsum[blockIdx.x];
#pragma unroll
    for (int k = 0; k < 8; ++k) {
        int idx = base + k;
        int o = texcl + vals[k];
        if (idx <= N) off[idx] = o;
    }
    __syncthreads();
#pragma unroll
    for (int k = 0; k < 8; ++k) {
        int idx = base + k;
        int o = texcl + vals[k];
        if (idx < N) cnt[idx] = o;
    }
}

// ---------------------------------------------------------------------------
// Reorder edges into CSR-by-target, packed (row, weight) int2
// ---------------------------------------------------------------------------
__global__ __launch_bounds__(256)
void reorder_kernel(const int* __restrict__ row, const int* __restrict__ col,
                    const float* __restrict__ w, int* __restrict__ cursor,
                    int2* __restrict__ edgeRW, int E) {
    int e = blockIdx.x * blockDim.x + threadIdx.x;
    if (e < E) {
        int c = col[e];
        int pos = atomicAdd(&cursor[c], 1);
        edgeRW[pos] = make_int2(row[e], __builtin_bit_cast(int, w[e]));
    }
}

// ---------------------------------------------------------------------------
// MFMA dual GEMM:  h = x@Wg ; f = x@Wf  (A shared, bf16 matrix cores)
//   epilogue:  hsb  = bf16(dinv*h)
//              accb = bf16( leaky(f + bf) + bg + dinv*(dinv*h) )
// ---------------------------------------------------------------------------
__global__ __launch_bounds__(256, 2)
void gemm_mfma_kernel(const float* __restrict__ x_src, const float* __restrict__ x_tar,
                      int n_src, int n_total,
                      const unsigned short* __restrict__ WgT,
                      const unsigned short* __restrict__ WfT,
                      const float* __restrict__ bg, const float* __restrict__ bf,
                      const float* __restrict__ dinv,
                      unsigned short* __restrict__ hsb,
                      unsigned short* __restrict__ accb)
{
    __shared__ unsigned short Ash[128 * 128];   // 32 KB bf16

    const int t = threadIdx.x;

    // ---- stage A: 128 rows x 128 f32 -> bf16, swizzled ----
#pragma unroll
    for (int s = 0; s < 8; ++s) {
        int id  = t + s * 256;        // 0..2047 chunk id
        int row = id >> 4;            // 0..127
        int c   = id & 15;            // 16B chunk within row
        int rg  = blockIdx.x * 128 + row;
        if (rg > n_total - 1) rg = n_total - 1;
        const float* xr = (rg < n_src) ? x_src + (size_t)rg * DIM
                                       : x_tar + (size_t)(rg - n_src) * DIM;
        float4 v0 = *(const float4*)(xr + c * 8);
        float4 v1 = *(const float4*)(xr + c * 8 + 4);
        union { uint4 q; unsigned short us[8]; } cv;
        cv.us[0] = f2bf(v0.x); cv.us[1] = f2bf(v0.y);
        cv.us[2] = f2bf(v0.z); cv.us[3] = f2bf(v0.w);
        cv.us[4] = f2bf(v1.x); cv.us[5] = f2bf(v1.y);
        cv.us[6] = f2bf(v1.z); cv.us[7] = f2bf(v1.w);
        *(uint4*)&Ash[(size_t)row * 128 + ((c ^ (row & 15)) * 8)] = cv.q;
    }
    __syncthreads();

    const int lane = t & 63;
    const int wave = t >> 6;
    const int wr = wave >> 1;         // row half (0..1)
    const int wc = wave & 1;          // col half (0..1)
    const int lr = lane & 15;
    const int lk = lane >> 4;

    f32x4 accg[4][4], accf[4][4];
#pragma unroll
    for (int i = 0; i < 4; ++i)
#pragma unroll
        for (int j = 0; j < 4; ++j) {
            accg[i][j] = (f32x4)0.0f;
            accf[i][j] = (f32x4)0.0f;
        }

#pragma unroll
    for (int ks = 0; ks < 4; ++ks) {
        short8v a[4];
#pragma unroll
        for (int mf = 0; mf < 4; ++mf) {
            int row = wr * 64 + mf * 16 + lr;      // A row, lane&15
            int cc  = ks * 4 + lk;                 // chunk = k/8
            a[mf] = *(const short8v*)&Ash[(size_t)row * 128 + ((cc ^ (row & 15)) * 8)];
        }
#pragma unroll
        for (int nf = 0; nf < 4; ++nf) {
            int col = wc * 64 + nf * 16 + lr;
            const size_t bo = (size_t)col * 128 + ks * 32 + lk * 8;
            short8v bgv = *(const short8v*)(WgT + bo);
            short8v bfv = *(const short8v*)(WfT + bo);
#pragma unroll
            for (int mf = 0; mf < 4; ++mf) {
                accg[mf][nf] = __builtin_amdgcn_mfma_f32_16x16x32_bf16(a[mf], bgv, accg[mf][nf], 0, 0, 0);
                accf[mf][nf] = __builtin_amdgcn_mfma_f32_16x16x32_bf16(a[mf], bfv, accf[mf][nf], 0, 0, 0);
            }
        }
    }

    // ---- epilogue: C/D layout col=lane&15, row=(lane>>4)*4+reg ----
#pragma unroll
    for (int mf = 0; mf < 4; ++mf) {
        int r0 = blockIdx.x * 128 + wr * 64 + mf * 16 + lk * 4;
        if (r0 >= n_total) continue;               // N%4==0 -> r0+3 < N
        float4 dv4 = *(const float4*)(dinv + r0);
#pragma unroll
        for (int nf = 0; nf < 4; ++nf) {
            int col = wc * 64 + nf * 16 + lr;
            float bgv = bg[col];
            float bfv = bf[col];
#pragma unroll
            for (int q = 0; q < 4; ++q) {
                size_t r  = (size_t)r0 + q;
                float dv  = ((const float*)&dv4)[q];
                float h   = accg[mf][nf][q];
                float f   = accf[mf][nf][q] + bfv;
                float hsv = dv * h;
                hsb[r * DIM + col]  = f2bf(hsv);
                accb[r * DIM + col] = f2bf(leaky(f) + bgv + dv * hsv);
            }
        }
    }
}

// ---------------------------------------------------------------------------
// Gather + fused layernorm + leaky_relu.
// 4 nodes per wave: 16 lanes x 8 dims each (16B uint4 gathers).
// Software-pipelined: meta 2 ahead, gather 1 ahead; predication via w=0.
//   out[i] = norm( accb[i] + dinv[i] * sum_{e->i} w_e * hsb[row_e] )
// ---------------------------------------------------------------------------
__global__ __launch_bounds__(256)
void gather_norm_kernel(const int* __restrict__ off, const int2* __restrict__ edgeRW,
                        const float* __restrict__ dinv,
                        const unsigned short* __restrict__ hsb,
                        const unsigned short* __restrict__ accb,
                        float* __restrict__ out, int n)
{
    const int wid  = threadIdx.x >> 6;
    const int lane = threadIdx.x & 63;
    const int sub  = lane >> 4;       // node within wave (0..3)
    const int sl   = lane & 15;       // lane within node, owns dims sl*8..+7
    int i = (blockIdx.x * 4 + wid) * 4 + sub;
    if (i >= n) i = n - 1;            // n % 16 == 0 in practice

    const int start = off[i];
    const int degc  = off[i + 1] - start;

    int md = degc;
    md = max(md, __shfl_xor(md, 16, 64));
    md = max(md, __shfl_xor(md, 32, 64));

    float s[8];
#pragma unroll
    for (int k = 0; k < 8; ++k) s[k] = 0.0f;

    const unsigned short* gbase = hsb + (size_t)sl * 8;

    // pipeline prologue
    int   r0 = 0, r1 = 0;
    float w0 = 0.0f, w1 = 0.0f;
    if (0 < degc) { int2 m = edgeRW[start];     r0 = m.x; w0 = __builtin_bit_cast(float, m.y); }
    if (1 < degc) { int2 m = edgeRW[start + 1]; r1 = m.x; w1 = __builtin_bit_cast(float, m.y); }
    uint4 p0 = *(const uint4*)(gbase + (size_t)r0 * DIM);

    for (int t = 0; t < md; ++t) {
        uint4 p1 = p0;
        if (t + 1 < md)                                   // wave-uniform branch
            p1 = *(const uint4*)(gbase + (size_t)r1 * DIM);
        int r2 = 0; float w2 = 0.0f;
        if (t + 2 < md) {
            if (t + 2 < degc) {                           // per-subgroup predicate
                int2 m = edgeRW[start + t + 2];
                r2 = m.x; w2 = __builtin_bit_cast(float, m.y);
            }
        }
        s[0] += w0 * bf2f_lo(p0.x); s[1] += w0 * bf2f_hi(p0.x);
        s[2] += w0 * bf2f_lo(p0.y); s[3] += w0 * bf2f_hi(p0.y);
        s[4] += w0 * bf2f_lo(p0.z); s[5] += w0 * bf2f_hi(p0.z);
        s[6] += w0 * bf2f_lo(p0.w); s[7] += w0 * bf2f_hi(p0.w);
        p0 = p1;
        r0 = r1; w0 = w1;
        r1 = r2; w1 = w2;
    }

    const float dv = dinv[i];
    uint4 av = *(const uint4*)(accb + (size_t)i * DIM + sl * 8);
    float v[8];
    v[0] = bf2f_lo(av.x) + dv * s[0]; v[1] = bf2f_hi(av.x) + dv * s[1];
    v[2] = bf2f_lo(av.y) + dv * s[2]; v[3] = bf2f_hi(av.y) + dv * s[3];
    v[4] = bf2f_lo(av.z) + dv * s[4]; v[5] = bf2f_hi(av.z) + dv * s[5];
    v[6] = bf2f_lo(av.w) + dv * s[6]; v[7] = bf2f_hi(av.w) + dv * s[7];

    float sum = 0.0f;
#pragma unroll
    for (int k = 0; k < 8; ++k) sum += v[k];
#pragma unroll
    for (int m = 1; m < 16; m <<= 1) sum += __shfl_xor(sum, m, 64);
    const float mean = sum * (1.0f / 128.0f);

    float sq = 0.0f;
#pragma unroll
    for (int k = 0; k < 8; ++k) {
        v[k] -= mean;
        sq += v[k] * v[k];
    }
#pragma unroll
    for (int m = 1; m < 16; m <<= 1) sq += __shfl_xor(sq, m, 64);
    const float rstd = rsqrtf(sq * (1.0f / 128.0f) + 1e-6f);

    float4 o1, o2;
    o1.x = leaky(v[0] * rstd); o1.y = leaky(v[1] * rstd);
    o1.z = leaky(v[2] * rstd); o1.w = leaky(v[3] * rstd);
    o2.x = leaky(v[4] * rstd); o2.y = leaky(v[5] * rstd);
    o2.z = leaky(v[6] * rstd); o2.w = leaky(v[7] * rstd);
    float* op = out + (size_t)i * DIM + sl * 8;
    *(float4*)op       = o1;
    *(float4*)(op + 4) = o2;
}

// ---------------------------------------------------------------------------
extern "C" void kernel_launch(void* const* d_in, const int* in_sizes, int n_in,
                              void* d_out, int out_size, void* d_ws, size_t ws_size,
                              hipStream_t stream)
{
    const float* x_src = (const float*)d_in[0];
    const float* x_tar = (const float*)d_in[1];
    const int*   ei    = (const int*)d_in[2];
    const float* ew    = (const float*)d_in[3];
    const float* Wg    = (const float*)d_in[4];
    const float* bg    = (const float*)d_in[5];
    const float* Wf    = (const float*)d_in[6];
    const float* bf    = (const float*)d_in[7];

    const int n_src = in_sizes[0] / DIM;
    const int n_tar = in_sizes[1] / DIM;
    const int N     = n_src + n_tar;
    const int E     = in_sizes[3];

    const int* rowp = ei;       // edge_index[0] = message source
    const int* colp = ei + E;   // edge_index[1] = message target

    // ---- workspace layout ----
    char* p = (char*)d_ws;
    float* dinv = (float*)p;  p += (size_t)N * 4;          // deg -> dinv in place
    int*   cnt  = (int*)p;    p += (size_t)N * 4;
    int*   off  = (int*)p;    p += (size_t)(N + 1) * 4;
    int*   bsum = (int*)p;    p += 160 * 4;
    p = (char*)(((uintptr_t)p + 15) & ~(uintptr_t)15);
    int2*  edgeRW = (int2*)p; p += (size_t)E * 8;
    unsigned short* hsb  = (unsigned short*)p; p += (size_t)N * DIM * 2;
    unsigned short* accb = (unsigned short*)p; p += (size_t)N * DIM * 2;
    unsigned short* WgT  = (unsigned short*)p; p += 128 * 128 * 2;
    unsigned short* WfT  = (unsigned short*)p;

    const int NB = (N + 1 + SCAN_CHUNK - 1) / SCAN_CHUNK;

    hipMemsetAsync(dinv, 0, (size_t)2 * N * sizeof(float), stream);  // deg + cnt

    wprep_kernel<<<64, 256, 0, stream>>>(Wg, Wf, WgT, WfT);

    hist_deg_kernel<<<(E + 255) / 256, 256, 0, stream>>>(colp, ew, cnt, dinv, E);

    dinv_kernel<<<(N + 255) / 256, 256, 0, stream>>>(dinv, N);

    scan_block_sums<<<NB, 256, 0, stream>>>(cnt, bsum, N);
    scan_bsum_kernel<<<1, 128, 0, stream>>>(bsum, NB);
    scan_write_kernel<<<NB, 256, 0, stream>>>(cnt, bsum, off, N);

    reorder_kernel<<<(E + 255) / 256, 256, 0, stream>>>(rowp, colp, ew, cnt,
                                                        edgeRW, E);

    gemm_mfma_kernel<<<(N + 127) / 128, 256, 0, stream>>>(
        x_src, x_tar, n_src, N, WgT, WfT, bg, bf, dinv, hsb, accb);

    gather_norm_kernel<<<(N + 15) / 16, 256, 0, stream>>>(
        off, edgeRW, dinv, hsb, accb, (float*)d_out, N);
}

// Round 5
// 221.359 us; speedup vs baseline: 6.3275x; 1.1152x over previous
//
#include <hip/hip_runtime.h>
#include <hip/hip_bf16.h>
#include <cstddef>
#include <cstdint>

#define DIM 128
#define SCAN_CHUNK 2048   // 256 threads x 8 elems

typedef __attribute__((ext_vector_type(8))) short short8v;  // 8 bf16 (4 VGPR)
typedef __attribute__((ext_vector_type(4))) float f32x4;    // MFMA acc

__device__ __forceinline__ float leaky(float v) {
    return v > 0.0f ? v : 0.01f * v;
}

__device__ __forceinline__ unsigned short f2bf(float f) {
    unsigned u = __builtin_bit_cast(unsigned, f);
    u += 0x7FFF + ((u >> 16) & 1);      // round-to-nearest-even
    return (unsigned short)(u >> 16);
}

// pack two f32 -> one u32 of 2 bf16 (lo = a, hi = b), single HW instr
__device__ __forceinline__ unsigned cvt_pk_bf16(float a, float b) {
    unsigned r;
    asm("v_cvt_pk_bf16_f32 %0, %1, %2" : "=v"(r) : "v"(a), "v"(b));
    return r;
}

__device__ __forceinline__ float bf2f_hi(unsigned p) {
    return __builtin_bit_cast(float, p & 0xFFFF0000u);
}
__device__ __forceinline__ float bf2f_lo(unsigned p) {
    return __builtin_bit_cast(float, p << 16);
}

// ---------------------------------------------------------------------------
// init: zero cnt[]  +  W transpose/convert (first 64 blocks' threads)
// ---------------------------------------------------------------------------
__global__ __launch_bounds__(256)
void init_kernel(const float* __restrict__ Wg, const float* __restrict__ Wf,
                 unsigned short* __restrict__ WgT, unsigned short* __restrict__ WfT,
                 int* __restrict__ cnt, int N) {
    int t = blockIdx.x * 256 + threadIdx.x;
    if (t < N) cnt[t] = 0;
    if (t < 128 * 128) {
        int col = t >> 7, k = t & 127;
        WgT[col * 128 + k] = f2bf(Wg[k * 128 + col]);
        WfT[col * 128 + k] = f2bf(Wf[k * 128 + col]);
    }
}

// ---------------------------------------------------------------------------
// histogram of in-degree counts (int only; weighted degree comes from CSR)
// ---------------------------------------------------------------------------
__global__ __launch_bounds__(256)
void hist_kernel(const int* __restrict__ col, int* __restrict__ cnt, int E) {
    int e = blockIdx.x * blockDim.x + threadIdx.x;
    if (e < E) atomicAdd(&cnt[col[e]], 1);
}

// ---------------------------------------------------------------------------
// Scan pass 1: per-chunk sums of cnt
// ---------------------------------------------------------------------------
__global__ __launch_bounds__(256)
void scan_block_sums(const int* __restrict__ cnt, int* __restrict__ bsum, int N) {
    __shared__ int sdata[4];
    int base = blockIdx.x * SCAN_CHUNK;
    int s = 0;
    for (int k = threadIdx.x; k < SCAN_CHUNK; k += 256) {
        int idx = base + k;
        s += (idx < N) ? cnt[idx] : 0;
    }
#pragma unroll
    for (int m = 1; m < 64; m <<= 1) s += __shfl_xor(s, m, 64);
    if ((threadIdx.x & 63) == 0) sdata[threadIdx.x >> 6] = s;
    __syncthreads();
    if (threadIdx.x == 0)
        bsum[blockIdx.x] = sdata[0] + sdata[1] + sdata[2] + sdata[3];
}

// ---------------------------------------------------------------------------
// Scan pass 2: exclusive scan of chunk sums (nb <= 128)
// ---------------------------------------------------------------------------
__global__ __launch_bounds__(128)
void scan_bsum_kernel(int* __restrict__ bsum, int nb) {
    __shared__ int wtot[2];
    int t = threadIdx.x;
    int lane = t & 63;
    int orig = (t < nb) ? bsum[t] : 0;
    int v = orig;
#pragma unroll
    for (int m = 1; m < 64; m <<= 1) {
        int u = __shfl_up(v, m, 64);
        if (lane >= m) v += u;
    }
    if (lane == 63) wtot[t >> 6] = v;
    __syncthreads();
    if (t >= 64) v += wtot[0];
    if (t < nb) bsum[t] = v - orig;   // exclusive
}

// ---------------------------------------------------------------------------
// Scan pass 3: exclusive scan -> off[0..N], cursor copy into cnt[]
// ---------------------------------------------------------------------------
__global__ __launch_bounds__(256)
void scan_write_kernel(int* __restrict__ cnt, const int* __restrict__ bsum,
                       int* __restrict__ off, int N) {
    __shared__ int wsum[4];
    int t = threadIdx.x;
    int base = blockIdx.x * SCAN_CHUNK + t * 8;
    int vals[8];
    int local = 0;
#pragma unroll
    for (int k = 0; k < 8; ++k) {
        int idx = base + k;
        int c = (idx < N) ? cnt[idx] : 0;
        vals[k] = local;
        local += c;
    }
    int tsum = local;
    int lane = t & 63;
    int v = tsum;
#pragma unroll
    for (int m = 1; m < 64; m <<= 1) {
        int u = __shfl_up(v, m, 64);
        if (lane >= m) v += u;
    }
    if (lane == 63) wsum[t >> 6] = v;
    __syncthreads();
    int woff = 0;
    for (int i = 0; i < (t >> 6); ++i) woff += wsum[i];
    int texcl = (v - tsum) + woff + bsum[blockIdx.x];
#pragma unroll
    for (int k = 0; k < 8; ++k) {
        int idx = base + k;
        int o = texcl + vals[k];
        if (idx <= N) off[idx] = o;
    }
    __syncthreads();
#pragma unroll
    for (int k = 0; k < 8; ++k) {
        int idx = base + k;
        int o = texcl + vals[k];
        if (idx < N) cnt[idx] = o;
    }
}

// ---------------------------------------------------------------------------
// Reorder edges into CSR-by-target, packed (row, weight) int2
// ---------------------------------------------------------------------------
__global__ __launch_bounds__(256)
void reorder_kernel(const int* __restrict__ row, const int* __restrict__ col,
                    const float* __restrict__ w, int* __restrict__ cursor,
                    int2* __restrict__ edgeRW, int E) {
    int e = blockIdx.x * blockDim.x + threadIdx.x;
    if (e < E) {
        int c = col[e];
        int pos = atomicAdd(&cursor[c], 1);
        edgeRW[pos] = make_int2(row[e], __builtin_bit_cast(int, w[e]));
    }
}

// ---------------------------------------------------------------------------
// dinv from CSR: dinv[i] = rsqrt(1 + sum_j w_j)   (self-loop folded)
// ---------------------------------------------------------------------------
__global__ __launch_bounds__(256)
void csr_dinv_kernel(const int* __restrict__ off, const int2* __restrict__ edgeRW,
                     float* __restrict__ dinv, int N) {
    int i = blockIdx.x * 256 + threadIdx.x;
    if (i >= N) return;
    int s = off[i], e = off[i + 1];
    float acc = 1.0f;
    for (int j = s; j < e; ++j)
        acc += __builtin_bit_cast(float, edgeRW[j].y);
    dinv[i] = rsqrtf(acc);
}

// ---------------------------------------------------------------------------
// MFMA dual GEMM:  h = x@Wg ; f = x@Wf  (A shared, bf16 matrix cores)
// Operands SWAPPED vs naive: mfma(W_frag, x_frag) so D gives each lane
//   row = lane&15 (one x-row), cols = (lane>>4)*4 + q (4 CONSECUTIVE cols)
// -> epilogue packs 4 bf16 into one 8 B dwordx2 store per fragment.
//   hsb  = bf16(dinv*h)
//   accb = bf16( leaky(f + bf) + bg + dinv*(dinv*h) )
// ---------------------------------------------------------------------------
__global__ __launch_bounds__(256, 2)
void gemm_mfma_kernel(const float* __restrict__ x_src, const float* __restrict__ x_tar,
                      int n_src, int n_total,
                      const unsigned short* __restrict__ WgT,
                      const unsigned short* __restrict__ WfT,
                      const float* __restrict__ bg, const float* __restrict__ bf,
                      const float* __restrict__ dinv,
                      unsigned short* __restrict__ hsb,
                      unsigned short* __restrict__ accb)
{
    __shared__ unsigned short Ash[128 * 128];   // 32 KB bf16

    const int t = threadIdx.x;

    // ---- stage A: 128 rows x 128 f32 -> bf16, swizzled ----
#pragma unroll
    for (int s = 0; s < 8; ++s) {
        int id  = t + s * 256;        // 0..2047 chunk id
        int row = id >> 4;            // 0..127
        int c   = id & 15;            // 16B chunk within row
        int rg  = blockIdx.x * 128 + row;
        if (rg > n_total - 1) rg = n_total - 1;
        const float* xr = (rg < n_src) ? x_src + (size_t)rg * DIM
                                       : x_tar + (size_t)(rg - n_src) * DIM;
        float4 v0 = *(const float4*)(xr + c * 8);
        float4 v1 = *(const float4*)(xr + c * 8 + 4);
        union { uint4 q; unsigned short us[8]; } cv;
        cv.us[0] = f2bf(v0.x); cv.us[1] = f2bf(v0.y);
        cv.us[2] = f2bf(v0.z); cv.us[3] = f2bf(v0.w);
        cv.us[4] = f2bf(v1.x); cv.us[5] = f2bf(v1.y);
        cv.us[6] = f2bf(v1.z); cv.us[7] = f2bf(v1.w);
        *(uint4*)&Ash[(size_t)row * 128 + ((c ^ (row & 15)) * 8)] = cv.q;
    }
    __syncthreads();

    const int lane = t & 63;
    const int wave = t >> 6;
    const int wr = wave >> 1;         // row half (0..1)
    const int wc = wave & 1;          // col half (0..1)
    const int lr = lane & 15;
    const int lk = lane >> 4;

    f32x4 accg[4][4], accf[4][4];
#pragma unroll
    for (int i = 0; i < 4; ++i)
#pragma unroll
        for (int j = 0; j < 4; ++j) {
            accg[i][j] = (f32x4)0.0f;
            accf[i][j] = (f32x4)0.0f;
        }

#pragma unroll
    for (int ks = 0; ks < 4; ++ks) {
        short8v xf[4];                 // B-operand: x-row fragments
#pragma unroll
        for (int mf = 0; mf < 4; ++mf) {
            int row = wr * 64 + mf * 16 + lr;      // x row at lane&15
            int cc  = ks * 4 + lk;                 // chunk = k/8
            xf[mf] = *(const short8v*)&Ash[(size_t)row * 128 + ((cc ^ (row & 15)) * 8)];
        }
#pragma unroll
        for (int nf = 0; nf < 4; ++nf) {
            int col = wc * 64 + nf * 16 + lr;      // A-operand: W col at lane&15
            const size_t bo = (size_t)col * 128 + ks * 32 + lk * 8;
            short8v bgv = *(const short8v*)(WgT + bo);
            short8v bfv = *(const short8v*)(WfT + bo);
#pragma unroll
            for (int mf = 0; mf < 4; ++mf) {
                accg[mf][nf] = __builtin_amdgcn_mfma_f32_16x16x32_bf16(bgv, xf[mf], accg[mf][nf], 0, 0, 0);
                accf[mf][nf] = __builtin_amdgcn_mfma_f32_16x16x32_bf16(bfv, xf[mf], accf[mf][nf], 0, 0, 0);
            }
        }
    }

    // ---- epilogue: lane owns (row = ..+lr, cols c0..c0+3), 8 B stores ----
#pragma unroll
    for (int mf = 0; mf < 4; ++mf) {
        int r = blockIdx.x * 128 + wr * 64 + mf * 16 + lr;
        const bool valid = (r < n_total);
        int rc = valid ? r : (n_total - 1);
        float dv = dinv[rc];
#pragma unroll
        for (int nf = 0; nf < 4; ++nf) {
            int c0 = wc * 64 + nf * 16 + lk * 4;
            float4 bgv = *(const float4*)(bg + c0);
            float4 bfv = *(const float4*)(bf + c0);

            float hs0 = dv * accg[mf][nf][0];
            float hs1 = dv * accg[mf][nf][1];
            float hs2 = dv * accg[mf][nf][2];
            float hs3 = dv * accg[mf][nf][3];

            float o0 = leaky(accf[mf][nf][0] + bfv.x) + bgv.x + dv * hs0;
            float o1 = leaky(accf[mf][nf][1] + bfv.y) + bgv.y + dv * hs1;
            float o2 = leaky(accf[mf][nf][2] + bfv.z) + bgv.z + dv * hs2;
            float o3 = leaky(accf[mf][nf][3] + bfv.w) + bgv.w + dv * hs3;

            uint2 hp, op;
            hp.x = cvt_pk_bf16(hs0, hs1);
            hp.y = cvt_pk_bf16(hs2, hs3);
            op.x = cvt_pk_bf16(o0, o1);
            op.y = cvt_pk_bf16(o2, o3);

            if (valid) {
                *(uint2*)(hsb  + (size_t)r * DIM + c0) = hp;
                *(uint2*)(accb + (size_t)r * DIM + c0) = op;
            }
        }
    }
}

// ---------------------------------------------------------------------------
// Gather + fused layernorm + leaky_relu.
// 4 nodes per wave: 16 lanes x 8 dims each (16B uint4 gathers), pipelined.
//   out[i] = norm( accb[i] + dinv[i] * sum_{e->i} w_e * hsb[row_e] )
// ---------------------------------------------------------------------------
__global__ __launch_bounds__(256)
void gather_norm_kernel(const int* __restrict__ off, const int2* __restrict__ edgeRW,
                        const float* __restrict__ dinv,
                        const unsigned short* __restrict__ hsb,
                        const unsigned short* __restrict__ accb,
                        float* __restrict__ out, int n)
{
    const int wid  = threadIdx.x >> 6;
    const int lane = threadIdx.x & 63;
    const int sub  = lane >> 4;       // node within wave (0..3)
    const int sl   = lane & 15;       // lane within node, owns dims sl*8..+7
    int i = (blockIdx.x * 4 + wid) * 4 + sub;
    if (i >= n) i = n - 1;

    const int start = off[i];
    const int degc  = off[i + 1] - start;

    int md = degc;
    md = max(md, __shfl_xor(md, 16, 64));
    md = max(md, __shfl_xor(md, 32, 64));

    float s[8];
#pragma unroll
    for (int k = 0; k < 8; ++k) s[k] = 0.0f;

    const unsigned short* gbase = hsb + (size_t)sl * 8;

    int   r0 = 0, r1 = 0;
    float w0 = 0.0f, w1 = 0.0f;
    if (0 < degc) { int2 m = edgeRW[start];     r0 = m.x; w0 = __builtin_bit_cast(float, m.y); }
    if (1 < degc) { int2 m = edgeRW[start + 1]; r1 = m.x; w1 = __builtin_bit_cast(float, m.y); }
    uint4 p0 = *(const uint4*)(gbase + (size_t)r0 * DIM);

    for (int t = 0; t < md; ++t) {
        uint4 p1 = p0;
        if (t + 1 < md)
            p1 = *(const uint4*)(gbase + (size_t)r1 * DIM);
        int r2 = 0; float w2 = 0.0f;
        if (t + 2 < md) {
            if (t + 2 < degc) {
                int2 m = edgeRW[start + t + 2];
                r2 = m.x; w2 = __builtin_bit_cast(float, m.y);
            }
        }
        s[0] += w0 * bf2f_lo(p0.x); s[1] += w0 * bf2f_hi(p0.x);
        s[2] += w0 * bf2f_lo(p0.y); s[3] += w0 * bf2f_hi(p0.y);
        s[4] += w0 * bf2f_lo(p0.z); s[5] += w0 * bf2f_hi(p0.z);
        s[6] += w0 * bf2f_lo(p0.w); s[7] += w0 * bf2f_hi(p0.w);
        p0 = p1;
        r0 = r1; w0 = w1;
        r1 = r2; w1 = w2;
    }

    const float dv = dinv[i];
    uint4 av = *(const uint4*)(accb + (size_t)i * DIM + sl * 8);
    float v[8];
    v[0] = bf2f_lo(av.x) + dv * s[0]; v[1] = bf2f_hi(av.x) + dv * s[1];
    v[2] = bf2f_lo(av.y) + dv * s[2]; v[3] = bf2f_hi(av.y) + dv * s[3];
    v[4] = bf2f_lo(av.z) + dv * s[4]; v[5] = bf2f_hi(av.z) + dv * s[5];
    v[6] = bf2f_lo(av.w) + dv * s[6]; v[7] = bf2f_hi(av.w) + dv * s[7];

    float sum = 0.0f;
#pragma unroll
    for (int k = 0; k < 8; ++k) sum += v[k];
#pragma unroll
    for (int m = 1; m < 16; m <<= 1) sum += __shfl_xor(sum, m, 64);
    const float mean = sum * (1.0f / 128.0f);

    float sq = 0.0f;
#pragma unroll
    for (int k = 0; k < 8; ++k) {
        v[k] -= mean;
        sq += v[k] * v[k];
    }
#pragma unroll
    for (int m = 1; m < 16; m <<= 1) sq += __shfl_xor(sq, m, 64);
    const float rstd = rsqrtf(sq * (1.0f / 128.0f) + 1e-6f);

    float4 o1, o2;
    o1.x = leaky(v[0] * rstd); o1.y = leaky(v[1] * rstd);
    o1.z = leaky(v[2] * rstd); o1.w = leaky(v[3] * rstd);
    o2.x = leaky(v[4] * rstd); o2.y = leaky(v[5] * rstd);
    o2.z = leaky(v[6] * rstd); o2.w = leaky(v[7] * rstd);
    float* op = out + (size_t)i * DIM + sl * 8;
    *(float4*)op       = o1;
    *(float4*)(op + 4) = o2;
}

// ---------------------------------------------------------------------------
extern "C" void kernel_launch(void* const* d_in, const int* in_sizes, int n_in,
                              void* d_out, int out_size, void* d_ws, size_t ws_size,
                              hipStream_t stream)
{
    const float* x_src = (const float*)d_in[0];
    const float* x_tar = (const float*)d_in[1];
    const int*   ei    = (const int*)d_in[2];
    const float* ew    = (const float*)d_in[3];
    const float* Wg    = (const float*)d_in[4];
    const float* bg    = (const float*)d_in[5];
    const float* Wf    = (const float*)d_in[6];
    const float* bf    = (const float*)d_in[7];

    const int n_src = in_sizes[0] / DIM;
    const int n_tar = in_sizes[1] / DIM;
    const int N     = n_src + n_tar;
    const int E     = in_sizes[3];

    const int* rowp = ei;       // edge_index[0] = message source
    const int* colp = ei + E;   // edge_index[1] = message target

    // ---- workspace layout ----
    char* p = (char*)d_ws;
    float* dinv = (float*)p;  p += (size_t)N * 4;
    int*   cnt  = (int*)p;    p += (size_t)N * 4;
    int*   off  = (int*)p;    p += (size_t)(N + 1) * 4;
    int*   bsum = (int*)p;    p += 160 * 4;
    p = (char*)(((uintptr_t)p + 15) & ~(uintptr_t)15);
    int2*  edgeRW = (int2*)p; p += (size_t)E * 8;
    unsigned short* hsb  = (unsigned short*)p; p += (size_t)N * DIM * 2;
    unsigned short* accb = (unsigned short*)p; p += (size_t)N * DIM * 2;
    unsigned short* WgT  = (unsigned short*)p; p += 128 * 128 * 2;
    unsigned short* WfT  = (unsigned short*)p;

    const int NB = (N + 1 + SCAN_CHUNK - 1) / SCAN_CHUNK;

    init_kernel<<<(N + 255) / 256, 256, 0, stream>>>(Wg, Wf, WgT, WfT, cnt, N);

    hist_kernel<<<(E + 255) / 256, 256, 0, stream>>>(colp, cnt, E);

    scan_block_sums<<<NB, 256, 0, stream>>>(cnt, bsum, N);
    scan_bsum_kernel<<<1, 128, 0, stream>>>(bsum, NB);
    scan_write_kernel<<<NB, 256, 0, stream>>>(cnt, bsum, off, N);

    reorder_kernel<<<(E + 255) / 256, 256, 0, stream>>>(rowp, colp, ew, cnt,
                                                        edgeRW, E);

    csr_dinv_kernel<<<(N + 255) / 256, 256, 0, stream>>>(off, edgeRW, dinv, N);

    gemm_mfma_kernel<<<(N + 127) / 128, 256, 0, stream>>>(
        x_src, x_tar, n_src, N, WgT, WfT, bg, bf, dinv, hsb, accb);

    gather_norm_kernel<<<(N + 15) / 16, 256, 0, stream>>>(
        off, edgeRW, dinv, hsb, accb, (float*)d_out, N);
}

// Round 6
// 216.340 us; speedup vs baseline: 6.4742x; 1.0232x over previous
//
#include <hip/hip_runtime.h>
#include <hip/hip_bf16.h>
#include <cstddef>
#include <cstdint>

#define DIM 128
#define SCAN_CHUNK 2048   // 256 threads x 8 elems

typedef __attribute__((ext_vector_type(8))) short short8v;  // 8 bf16 (4 VGPR)
typedef __attribute__((ext_vector_type(4))) float f32x4;    // MFMA acc

__device__ __forceinline__ float leaky(float v) {
    return v > 0.0f ? v : 0.01f * v;
}

__device__ __forceinline__ unsigned short f2bf(float f) {
    unsigned u = __builtin_bit_cast(unsigned, f);
    u += 0x7FFF + ((u >> 16) & 1);      // round-to-nearest-even
    return (unsigned short)(u >> 16);
}

// pack two f32 -> one u32 of 2 bf16 (lo = a, hi = b), single HW instr
__device__ __forceinline__ unsigned cvt_pk_bf16(float a, float b) {
    unsigned r;
    asm("v_cvt_pk_bf16_f32 %0, %1, %2" : "=v"(r) : "v"(a), "v"(b));
    return r;
}

__device__ __forceinline__ float bf2f_hi(unsigned p) {
    return __builtin_bit_cast(float, p & 0xFFFF0000u);
}
__device__ __forceinline__ float bf2f_lo(unsigned p) {
    return __builtin_bit_cast(float, p << 16);
}

// ---------------------------------------------------------------------------
// init: zero cnt[]  +  W transpose/convert
// ---------------------------------------------------------------------------
__global__ __launch_bounds__(256)
void init_kernel(const float* __restrict__ Wg, const float* __restrict__ Wf,
                 unsigned short* __restrict__ WgT, unsigned short* __restrict__ WfT,
                 int* __restrict__ cnt, int N) {
    int t = blockIdx.x * 256 + threadIdx.x;
    if (t < N) cnt[t] = 0;
    if (t < 128 * 128) {
        int col = t >> 7, k = t & 127;
        WgT[col * 128 + k] = f2bf(Wg[k * 128 + col]);
        WfT[col * 128 + k] = f2bf(Wf[k * 128 + col]);
    }
}

// ---------------------------------------------------------------------------
// histogram of in-degree counts
// ---------------------------------------------------------------------------
__global__ __launch_bounds__(256)
void hist_kernel(const int* __restrict__ col, int* __restrict__ cnt, int E) {
    int e = blockIdx.x * blockDim.x + threadIdx.x;
    if (e < E) atomicAdd(&cnt[col[e]], 1);
}

// ---------------------------------------------------------------------------
// Scan pass 1: per-chunk sums of cnt
// ---------------------------------------------------------------------------
__global__ __launch_bounds__(256)
void scan_block_sums(const int* __restrict__ cnt, int* __restrict__ bsum, int N) {
    __shared__ int sdata[4];
    int base = blockIdx.x * SCAN_CHUNK;
    int s = 0;
    for (int k = threadIdx.x; k < SCAN_CHUNK; k += 256) {
        int idx = base + k;
        s += (idx < N) ? cnt[idx] : 0;
    }
#pragma unroll
    for (int m = 1; m < 64; m <<= 1) s += __shfl_xor(s, m, 64);
    if ((threadIdx.x & 63) == 0) sdata[threadIdx.x >> 6] = s;
    __syncthreads();
    if (threadIdx.x == 0)
        bsum[blockIdx.x] = sdata[0] + sdata[1] + sdata[2] + sdata[3];
}

// ---------------------------------------------------------------------------
// Scan pass 2: exclusive scan of chunk sums (nb <= 128)
// ---------------------------------------------------------------------------
__global__ __launch_bounds__(128)
void scan_bsum_kernel(int* __restrict__ bsum, int nb) {
    __shared__ int wtot[2];
    int t = threadIdx.x;
    int lane = t & 63;
    int orig = (t < nb) ? bsum[t] : 0;
    int v = orig;
#pragma unroll
    for (int m = 1; m < 64; m <<= 1) {
        int u = __shfl_up(v, m, 64);
        if (lane >= m) v += u;
    }
    if (lane == 63) wtot[t >> 6] = v;
    __syncthreads();
    if (t >= 64) v += wtot[0];
    if (t < nb) bsum[t] = v - orig;   // exclusive
}

// ---------------------------------------------------------------------------
// Scan pass 3: exclusive scan -> off[0..N], cursor copy into cnt[]
// ---------------------------------------------------------------------------
__global__ __launch_bounds__(256)
void scan_write_kernel(int* __restrict__ cnt, const int* __restrict__ bsum,
                       int* __restrict__ off, int N) {
    __shared__ int wsum[4];
    int t = threadIdx.x;
    int base = blockIdx.x * SCAN_CHUNK + t * 8;
    int vals[8];
    int local = 0;
#pragma unroll
    for (int k = 0; k < 8; ++k) {
        int idx = base + k;
        int c = (idx < N) ? cnt[idx] : 0;
        vals[k] = local;
        local += c;
    }
    int tsum = local;
    int lane = t & 63;
    int v = tsum;
#pragma unroll
    for (int m = 1; m < 64; m <<= 1) {
        int u = __shfl_up(v, m, 64);
        if (lane >= m) v += u;
    }
    if (lane == 63) wsum[t >> 6] = v;
    __syncthreads();
    int woff = 0;
    for (int i = 0; i < (t >> 6); ++i) woff += wsum[i];
    int texcl = (v - tsum) + woff + bsum[blockIdx.x];
#pragma unroll
    for (int k = 0; k < 8; ++k) {
        int idx = base + k;
        int o = texcl + vals[k];
        if (idx <= N) off[idx] = o;
    }
    __syncthreads();
#pragma unroll
    for (int k = 0; k < 8; ++k) {
        int idx = base + k;
        int o = texcl + vals[k];
        if (idx < N) cnt[idx] = o;
    }
}

// ---------------------------------------------------------------------------
// Reorder edges into CSR-by-target, packed (row, weight) int2
// ---------------------------------------------------------------------------
__global__ __launch_bounds__(256)
void reorder_kernel(const int* __restrict__ row, const int* __restrict__ col,
                    const float* __restrict__ w, int* __restrict__ cursor,
                    int2* __restrict__ edgeRW, int E) {
    int e = blockIdx.x * blockDim.x + threadIdx.x;
    if (e < E) {
        int c = col[e];
        int pos = atomicAdd(&cursor[c], 1);
        edgeRW[pos] = make_int2(row[e], __builtin_bit_cast(int, w[e]));
    }
}

// ---------------------------------------------------------------------------
// dinv from CSR: dinv[i] = rsqrt(1 + sum_j w_j)
// ---------------------------------------------------------------------------
__global__ __launch_bounds__(256)
void csr_dinv_kernel(const int* __restrict__ off, const int2* __restrict__ edgeRW,
                     float* __restrict__ dinv, int N) {
    int i = blockIdx.x * 256 + threadIdx.x;
    if (i >= N) return;
    int s = off[i], e = off[i + 1];
    float acc = 1.0f;
    for (int j = s; j < e; ++j)
        acc += __builtin_bit_cast(float, edgeRW[j].y);
    dinv[i] = rsqrtf(acc);
}

// ---------------------------------------------------------------------------
// MFMA dual GEMM, 8 waves x (64 rows x 32 cols) per 128x128 block tile.
// Small acc tile (16 f32x4 = 64 regs) -> __launch_bounds__(512,4) targets
// 4 waves/SIMD resident (2x the R5 occupancy) to hide W/x load latency.
// Operands swapped: mfma(W_frag, x_frag); lane owns row lr, 4 consecutive
// cols -> 8 B packed bf16 stores.
//   hsb  = bf16(dinv*h) ; accb = bf16( leaky(f + bf) + bg + dinv*(dinv*h) )
// ---------------------------------------------------------------------------
__global__ __launch_bounds__(512, 4)
void gemm_mfma_kernel(const float* __restrict__ x_src, const float* __restrict__ x_tar,
                      int n_src, int n_total,
                      const unsigned short* __restrict__ WgT,
                      const unsigned short* __restrict__ WfT,
                      const float* __restrict__ bg, const float* __restrict__ bf,
                      const float* __restrict__ dinv,
                      unsigned short* __restrict__ hsb,
                      unsigned short* __restrict__ accb)
{
    __shared__ unsigned short Ash[128 * 128];   // 32 KB bf16

    const int t = threadIdx.x;

    // ---- stage A: 128 rows x 128 f32 -> bf16, swizzled (4 iters x 512) ----
#pragma unroll
    for (int s = 0; s < 4; ++s) {
        int id  = t + s * 512;        // 0..2047 chunk id
        int row = id >> 4;            // 0..127
        int c   = id & 15;            // 16B chunk within row
        int rg  = blockIdx.x * 128 + row;
        if (rg > n_total - 1) rg = n_total - 1;
        const float* xr = (rg < n_src) ? x_src + (size_t)rg * DIM
                                       : x_tar + (size_t)(rg - n_src) * DIM;
        float4 v0 = *(const float4*)(xr + c * 8);
        float4 v1 = *(const float4*)(xr + c * 8 + 4);
        union { uint4 q; unsigned short us[8]; } cv;
        cv.us[0] = f2bf(v0.x); cv.us[1] = f2bf(v0.y);
        cv.us[2] = f2bf(v0.z); cv.us[3] = f2bf(v0.w);
        cv.us[4] = f2bf(v1.x); cv.us[5] = f2bf(v1.y);
        cv.us[6] = f2bf(v1.z); cv.us[7] = f2bf(v1.w);
        *(uint4*)&Ash[(size_t)row * 128 + ((c ^ (row & 15)) * 8)] = cv.q;
    }
    __syncthreads();

    const int lane = t & 63;
    const int wave = t >> 6;          // 0..7
    const int wr = wave >> 2;         // row half (0..1): 64 rows
    const int wc = wave & 3;          // col quarter (0..3): 32 cols
    const int lr = lane & 15;
    const int lk = lane >> 4;

    f32x4 accg[4][2], accf[4][2];
#pragma unroll
    for (int i = 0; i < 4; ++i)
#pragma unroll
        for (int j = 0; j < 2; ++j) {
            accg[i][j] = (f32x4)0.0f;
            accf[i][j] = (f32x4)0.0f;
        }

#pragma unroll
    for (int ks = 0; ks < 4; ++ks) {
        short8v xf[4];                 // B-operand: x-row fragments
#pragma unroll
        for (int mf = 0; mf < 4; ++mf) {
            int row = wr * 64 + mf * 16 + lr;      // x row at lane&15
            int cc  = ks * 4 + lk;                 // chunk = k/8
            xf[mf] = *(const short8v*)&Ash[(size_t)row * 128 + ((cc ^ (row & 15)) * 8)];
        }
#pragma unroll
        for (int nf = 0; nf < 2; ++nf) {
            int col = wc * 32 + nf * 16 + lr;      // A-operand: W col at lane&15
            const size_t bo = (size_t)col * 128 + ks * 32 + lk * 8;
            short8v bgv = *(const short8v*)(WgT + bo);
            short8v bfv = *(const short8v*)(WfT + bo);
#pragma unroll
            for (int mf = 0; mf < 4; ++mf) {
                accg[mf][nf] = __builtin_amdgcn_mfma_f32_16x16x32_bf16(bgv, xf[mf], accg[mf][nf], 0, 0, 0);
                accf[mf][nf] = __builtin_amdgcn_mfma_f32_16x16x32_bf16(bfv, xf[mf], accf[mf][nf], 0, 0, 0);
            }
        }
    }

    // ---- epilogue: lane owns (row = ..+lr, cols c0..c0+3), 8 B stores ----
#pragma unroll
    for (int mf = 0; mf < 4; ++mf) {
        int r = blockIdx.x * 128 + wr * 64 + mf * 16 + lr;
        const bool valid = (r < n_total);
        int rc = valid ? r : (n_total - 1);
        float dv = dinv[rc];
#pragma unroll
        for (int nf = 0; nf < 2; ++nf) {
            int c0 = wc * 32 + nf * 16 + lk * 4;
            float4 bgv = *(const float4*)(bg + c0);
            float4 bfv = *(const float4*)(bf + c0);

            float hs0 = dv * accg[mf][nf][0];
            float hs1 = dv * accg[mf][nf][1];
            float hs2 = dv * accg[mf][nf][2];
            float hs3 = dv * accg[mf][nf][3];

            float o0 = leaky(accf[mf][nf][0] + bfv.x) + bgv.x + dv * hs0;
            float o1 = leaky(accf[mf][nf][1] + bfv.y) + bgv.y + dv * hs1;
            float o2 = leaky(accf[mf][nf][2] + bfv.z) + bgv.z + dv * hs2;
            float o3 = leaky(accf[mf][nf][3] + bfv.w) + bgv.w + dv * hs3;

            uint2 hp, op;
            hp.x = cvt_pk_bf16(hs0, hs1);
            hp.y = cvt_pk_bf16(hs2, hs3);
            op.x = cvt_pk_bf16(o0, o1);
            op.y = cvt_pk_bf16(o2, o3);

            if (valid) {
                *(uint2*)(hsb  + (size_t)r * DIM + c0) = hp;
                *(uint2*)(accb + (size_t)r * DIM + c0) = op;
            }
        }
    }
}

// ---------------------------------------------------------------------------
// Gather + fused layernorm + leaky_relu.
// 4 nodes per wave: 16 lanes x 8 dims each (16B uint4 gathers), pipelined.
//   out[i] = norm( accb[i] + dinv[i] * sum_{e->i} w_e * hsb[row_e] )
// ---------------------------------------------------------------------------
__global__ __launch_bounds__(256)
void gather_norm_kernel(const int* __restrict__ off, const int2* __restrict__ edgeRW,
                        const float* __restrict__ dinv,
                        const unsigned short* __restrict__ hsb,
                        const unsigned short* __restrict__ accb,
                        float* __restrict__ out, int n)
{
    const int wid  = threadIdx.x >> 6;
    const int lane = threadIdx.x & 63;
    const int sub  = lane >> 4;       // node within wave (0..3)
    const int sl   = lane & 15;       // lane within node, owns dims sl*8..+7
    int i = (blockIdx.x * 4 + wid) * 4 + sub;
    if (i >= n) i = n - 1;

    const int start = off[i];
    const int degc  = off[i + 1] - start;

    int md = degc;
    md = max(md, __shfl_xor(md, 16, 64));
    md = max(md, __shfl_xor(md, 32, 64));

    float s[8];
#pragma unroll
    for (int k = 0; k < 8; ++k) s[k] = 0.0f;

    const unsigned short* gbase = hsb + (size_t)sl * 8;

    int   r0 = 0, r1 = 0;
    float w0 = 0.0f, w1 = 0.0f;
    if (0 < degc) { int2 m = edgeRW[start];     r0 = m.x; w0 = __builtin_bit_cast(float, m.y); }
    if (1 < degc) { int2 m = edgeRW[start + 1]; r1 = m.x; w1 = __builtin_bit_cast(float, m.y); }
    uint4 p0 = *(const uint4*)(gbase + (size_t)r0 * DIM);

    for (int t = 0; t < md; ++t) {
        uint4 p1 = p0;
        if (t + 1 < md)
            p1 = *(const uint4*)(gbase + (size_t)r1 * DIM);
        int r2 = 0; float w2 = 0.0f;
        if (t + 2 < md) {
            if (t + 2 < degc) {
                int2 m = edgeRW[start + t + 2];
                r2 = m.x; w2 = __builtin_bit_cast(float, m.y);
            }
        }
        s[0] += w0 * bf2f_lo(p0.x); s[1] += w0 * bf2f_hi(p0.x);
        s[2] += w0 * bf2f_lo(p0.y); s[3] += w0 * bf2f_hi(p0.y);
        s[4] += w0 * bf2f_lo(p0.z); s[5] += w0 * bf2f_hi(p0.z);
        s[6] += w0 * bf2f_lo(p0.w); s[7] += w0 * bf2f_hi(p0.w);
        p0 = p1;
        r0 = r1; w0 = w1;
        r1 = r2; w1 = w2;
    }

    const float dv = dinv[i];
    uint4 av = *(const uint4*)(accb + (size_t)i * DIM + sl * 8);
    float v[8];
    v[0] = bf2f_lo(av.x) + dv * s[0]; v[1] = bf2f_hi(av.x) + dv * s[1];
    v[2] = bf2f_lo(av.y) + dv * s[2]; v[3] = bf2f_hi(av.y) + dv * s[3];
    v[4] = bf2f_lo(av.z) + dv * s[4]; v[5] = bf2f_hi(av.z) + dv * s[5];
    v[6] = bf2f_lo(av.w) + dv * s[6]; v[7] = bf2f_hi(av.w) + dv * s[7];

    float sum = 0.0f;
#pragma unroll
    for (int k = 0; k < 8; ++k) sum += v[k];
#pragma unroll
    for (int m = 1; m < 16; m <<= 1) sum += __shfl_xor(sum, m, 64);
    const float mean = sum * (1.0f / 128.0f);

    float sq = 0.0f;
#pragma unroll
    for (int k = 0; k < 8; ++k) {
        v[k] -= mean;
        sq += v[k] * v[k];
    }
#pragma unroll
    for (int m = 1; m < 16; m <<= 1) sq += __shfl_xor(sq, m, 64);
    const float rstd = rsqrtf(sq * (1.0f / 128.0f) + 1e-6f);

    float4 o1, o2;
    o1.x = leaky(v[0] * rstd); o1.y = leaky(v[1] * rstd);
    o1.z = leaky(v[2] * rstd); o1.w = leaky(v[3] * rstd);
    o2.x = leaky(v[4] * rstd); o2.y = leaky(v[5] * rstd);
    o2.z = leaky(v[6] * rstd); o2.w = leaky(v[7] * rstd);
    float* op = out + (size_t)i * DIM + sl * 8;
    *(float4*)op       = o1;
    *(float4*)(op + 4) = o2;
}

// ---------------------------------------------------------------------------
extern "C" void kernel_launch(void* const* d_in, const int* in_sizes, int n_in,
                              void* d_out, int out_size, void* d_ws, size_t ws_size,
                              hipStream_t stream)
{
    const float* x_src = (const float*)d_in[0];
    const float* x_tar = (const float*)d_in[1];
    const int*   ei    = (const int*)d_in[2];
    const float* ew    = (const float*)d_in[3];
    const float* Wg    = (const float*)d_in[4];
    const float* bg    = (const float*)d_in[5];
    const float* Wf    = (const float*)d_in[6];
    const float* bf    = (const float*)d_in[7];

    const int n_src = in_sizes[0] / DIM;
    const int n_tar = in_sizes[1] / DIM;
    const int N     = n_src + n_tar;
    const int E     = in_sizes[3];

    const int* rowp = ei;       // edge_index[0] = message source
    const int* colp = ei + E;   // edge_index[1] = message target

    // ---- workspace layout ----
    char* p = (char*)d_ws;
    float* dinv = (float*)p;  p += (size_t)N * 4;
    int*   cnt  = (int*)p;    p += (size_t)N * 4;
    int*   off  = (int*)p;    p += (size_t)(N + 1) * 4;
    int*   bsum = (int*)p;    p += 160 * 4;
    p = (char*)(((uintptr_t)p + 15) & ~(uintptr_t)15);
    int2*  edgeRW = (int2*)p; p += (size_t)E * 8;
    unsigned short* hsb  = (unsigned short*)p; p += (size_t)N * DIM * 2;
    unsigned short* accb = (unsigned short*)p; p += (size_t)N * DIM * 2;
    unsigned short* WgT  = (unsigned short*)p; p += 128 * 128 * 2;
    unsigned short* WfT  = (unsigned short*)p;

    const int NB = (N + 1 + SCAN_CHUNK - 1) / SCAN_CHUNK;

    init_kernel<<<(N + 255) / 256, 256, 0, stream>>>(Wg, Wf, WgT, WfT, cnt, N);

    hist_kernel<<<(E + 255) / 256, 256, 0, stream>>>(colp, cnt, E);

    scan_block_sums<<<NB, 256, 0, stream>>>(cnt, bsum, N);
    scan_bsum_kernel<<<1, 128, 0, stream>>>(bsum, NB);
    scan_write_kernel<<<NB, 256, 0, stream>>>(cnt, bsum, off, N);

    reorder_kernel<<<(E + 255) / 256, 256, 0, stream>>>(rowp, colp, ew, cnt,
                                                        edgeRW, E);

    csr_dinv_kernel<<<(N + 255) / 256, 256, 0, stream>>>(off, edgeRW, dinv, N);

    gemm_mfma_kernel<<<(N + 127) / 128, 512, 0, stream>>>(
        x_src, x_tar, n_src, N, WgT, WfT, bg, bf, dinv, hsb, accb);

    gather_norm_kernel<<<(N + 15) / 16, 256, 0, stream>>>(
        off, edgeRW, dinv, hsb, accb, (float*)d_out, N);
}